// Round 17
// baseline (690.143 us; speedup 1.0000x reference)
//
#include <hip/hip_runtime.h>
#include <cstdint>

// ---------------------------------------------------------------------------
// Types & helpers
// ---------------------------------------------------------------------------
typedef __attribute__((ext_vector_type(8))) short  bf16x8;   // 8 bf16 = 4 VGPR
typedef __attribute__((ext_vector_type(4))) float  f32x4;
typedef __attribute__((ext_vector_type(4))) unsigned int uint4v;
typedef __attribute__((ext_vector_type(2))) unsigned int uint2v;

typedef const __attribute__((address_space(1))) void* gas_t;
typedef __attribute__((address_space(3))) void* las_t;

__device__ __forceinline__ float bf2f(unsigned short b) {
    union { unsigned int u; float f; } v; v.u = ((unsigned int)b) << 16; return v.f;
}
__device__ __forceinline__ unsigned short f2bf(float f) {
    union { float f; unsigned int u; } v; v.f = f;
    unsigned int r = v.u + 0x7FFFu + ((v.u >> 16) & 1u);   // RNE
    return (unsigned short)(r >> 16);
}
__device__ __forceinline__ float u2f(unsigned int u) {
    union { unsigned int u; float f; } v; v.u = u; return v.f;
}

// ---------------------------------------------------------------------------
// Dequant block body: packed qw[K][NW] int4 -> Wt[N][K] bf16 (transposed).
// One block = 32 word-cols x 64 k. Thread owns 8k x 8n micro-tile.
// ---------------------------------------------------------------------------
__device__ __forceinline__ void dequant_block(int bx, int by, int t,
    const int* __restrict__ qw, const int* __restrict__ qz,
    const float* __restrict__ sc, unsigned short* __restrict__ out,
    int NW, int K)
{
    const int wcb = bx << 5;
    const int kb  = by << 6;
    const int g   = by >> 1;                  // AWQ group (G=128)
    const int N   = NW << 3;
    const int wc  = wcb + (t >> 3);
    const int k0  = kb + ((t & 7) << 3);

    unsigned int w[8];
#pragma unroll
    for (int j = 0; j < 8; j++) w[j] = (unsigned int)qw[(size_t)(k0 + j) * NW + wc];
    const unsigned int zw = (unsigned int)qz[(size_t)g * NW + wc];
    float scv[8];
#pragma unroll
    for (int j2 = 0; j2 < 8; j2++) scv[j2] = sc[(size_t)g * N + (wc << 3) + j2];

#pragma unroll
    for (int j2 = 0; j2 < 8; j2++) {
        const int sh = j2 << 2;
        const float s = scv[j2];
        const float moff = -(8388608.0f + (float)((zw >> sh) & 0xFu)) * s;
        unsigned int pk[4];
#pragma unroll
        for (int i = 0; i < 4; i++) {
            float f0 = fmaf(u2f(((w[2*i]   >> sh) & 0xFu) | 0x4B000000u), s, moff);
            float f1 = fmaf(u2f(((w[2*i+1] >> sh) & 0xFu) | 0x4B000000u), s, moff);
            asm("v_cvt_pk_bf16_f32 %0, %1, %2" : "=v"(pk[i]) : "v"(f0), "v"(f1));
        }
        uint4v ov = {pk[0], pk[1], pk[2], pk[3]};
        *(uint4v*)(out + (size_t)((wc << 3) + j2) * K + k0) = ov;
    }
}

// ---------------------------------------------------------------------------
// deq(qkv) + rmsnorm1 tail (independent work, one dispatch)
// ---------------------------------------------------------------------------
__global__ __launch_bounds__(256)
void deq_rms_kernel(const int* __restrict__ qw, const int* __restrict__ qz,
                    const float* __restrict__ sc, unsigned short* __restrict__ wout,
                    int NW, int K, int deqBlocks,
                    const float* __restrict__ x, const float* __restrict__ lnw,
                    unsigned short* __restrict__ xout)
{
    __shared__ float red[4];
    const int tid = threadIdx.x;
    if (blockIdx.x < (unsigned)deqBlocks) {
        int xb = NW >> 5;
        dequant_block(blockIdx.x % xb, blockIdx.x / xb, tid, qw, qz, sc, wout, NW, K);
        return;
    }
    const int t = blockIdx.x - deqBlocks;
    const float4* xr = (const float4*)(x + (size_t)t * 4096);
    float4 v[4];
    float ss = 0.f;
#pragma unroll
    for (int j = 0; j < 4; j++) {
        v[j] = xr[(j << 8) + tid];
        ss += v[j].x*v[j].x + v[j].y*v[j].y + v[j].z*v[j].z + v[j].w*v[j].w;
    }
#pragma unroll
    for (int m = 1; m < 64; m <<= 1) ss += __shfl_xor(ss, m);
    if ((tid & 63) == 0) red[tid >> 6] = ss;
    __syncthreads();
    float tot = red[0] + red[1] + red[2] + red[3];
    float rs = rsqrtf(tot * (1.f / 4096.f) + 1e-6f);
    const float4* wr = (const float4*)lnw;
#pragma unroll
    for (int j = 0; j < 4; j++) {
        float4 wv = wr[(j << 8) + tid];
        float4 xv = v[j];
        unsigned int p0 = (unsigned int)f2bf(xv.x*rs*wv.x) | ((unsigned int)f2bf(xv.y*rs*wv.y) << 16);
        unsigned int p1 = (unsigned int)f2bf(xv.z*rs*wv.z) | ((unsigned int)f2bf(xv.w*rs*wv.w) << 16);
        uint2v pk = {p0, p1};
        *(uint2v*)(&xout[(size_t)t*4096 + (size_t)(((j << 8) + tid) << 2)]) = pk;
    }
}

// ---------------------------------------------------------------------------
// Unified bf16 B^T GEMM (m97 structure, bijective XCD mapping) + dequant tail.
// GEMM: tile 128x128, BK=64, 4 waves, 32KB LDS, 4 blk/CU (lb 256,4 — proven;
// lb(256,5) capped VGPR at 48 and spilled acc -> 2x slowdown, R13).
//   xcd = flat&7, work = NB*xcd + (flat>>3), nb = work>>3, m = work&7.
// MODE 0: bf16 out0.  MODE 1: z picks (Bt0,out0)/(Bt1,out1), bf16.
// MODE 2: split-K by z (ksplit K each), bf16 partial at out0 + z*1024*N.
// MODE 5: split-K by z, fp32 atomicAdd into out0 (pre-initialized base).
// ---------------------------------------------------------------------------
template<int MODE>
__global__ __launch_bounds__(256, 4)
void bt_gemm(const unsigned short* __restrict__ A,
             const unsigned short* __restrict__ Bt0,
             const unsigned short* __restrict__ Bt1,
             void* __restrict__ out0, void* __restrict__ out1,
             int N, int K, int NB, int gemmBlocks, int ksplit,
             const int* dq1_qw, const int* dq1_qz, const float* dq1_sc,
             unsigned short* dq1_out, int dq1_NW, int dq1_K)
{
    const int flat = blockIdx.x;
    if (flat >= gemmBlocks) {
        if (blockIdx.z != 0) return;
        int db = flat - gemmBlocks;
        int xb = dq1_NW >> 5;
        dequant_block(db % xb, db / xb, threadIdx.x, dq1_qw, dq1_qz, dq1_sc, dq1_out, dq1_NW, dq1_K);
        return;
    }

    const int work = NB * (flat & 7) + (flat >> 3);
    const int n0 = (work >> 3) << 7;
    const int m0 = (work & 7) << 7;
    const int z  = blockIdx.z;

    const unsigned short* Bt = Bt0;
    void* outp = out0;
    if (MODE == 1 && z == 1) { Bt = Bt1; outp = out1; }
    const int k0base = (MODE == 2 || MODE == 5) ? z * ksplit : 0;
    const int nsteps = ((MODE == 2 || MODE == 5) ? ksplit : K) >> 6;

    __shared__ unsigned short As[128 * 64];   // 16KB
    __shared__ unsigned short Bs[128 * 64];   // 16KB

    const int tid  = threadIdx.x;
    const int lane = tid & 63;
    const int wid  = tid >> 6;
    const int wm   = wid >> 1, wn = wid & 1;

    f32x4 acc[4][4];
#pragma unroll
    for (int i = 0; i < 4; i++)
#pragma unroll
        for (int j = 0; j < 4; j++) { f32x4 zv = {0.f,0.f,0.f,0.f}; acc[i][j] = zv; }

    for (int t = 0; t < nsteps; t++) {
        const int k0 = k0base + (t << 6);
        __syncthreads();   // previous tile's reads complete
#pragma unroll
        for (int i = 0; i < 4; i++) {
            int slot = (i << 8) + tid;          // 0..1023
            int row = slot >> 3, s = slot & 7;
            __builtin_amdgcn_global_load_lds(
                (gas_t)(A + (size_t)(m0 + row) * K + k0 + ((s ^ (row & 7)) << 3)),
                (las_t)&As[slot << 3], 16, 0, 0);
        }
#pragma unroll
        for (int i = 0; i < 4; i++) {
            int slot = (i << 8) + tid;
            int row = slot >> 3, s = slot & 7;
            __builtin_amdgcn_global_load_lds(
                (gas_t)(Bt + (size_t)(n0 + row) * K + k0 + ((s ^ (row & 7)) << 3)),
                (las_t)&Bs[slot << 3], 16, 0, 0);
        }
        __syncthreads();   // drains vmcnt: tile resident
#pragma unroll
        for (int kk = 0; kk < 2; kk++) {
            const int srow = (kk << 2) + (lane >> 4);
            bf16x8 af[4], bfv[4];
#pragma unroll
            for (int mi = 0; mi < 4; mi++) {
                int r = (wm << 6) + (mi << 4) + (lane & 15);
                af[mi] = *(const bf16x8*)(&As[(r << 6) + ((srow ^ (r & 7)) << 3)]);
            }
#pragma unroll
            for (int ni = 0; ni < 4; ni++) {
                int r = (wn << 6) + (ni << 4) + (lane & 15);
                bfv[ni] = *(const bf16x8*)(&Bs[(r << 6) + ((srow ^ (r & 7)) << 3)]);
            }
#pragma unroll
            for (int mi = 0; mi < 4; mi++)
#pragma unroll
                for (int ni = 0; ni < 4; ni++)
                    acc[mi][ni] = __builtin_amdgcn_mfma_f32_16x16x32_bf16(af[mi], bfv[ni], acc[mi][ni], 0, 0, 0);
        }
    }

    // epilogue: C/D layout col=lane&15, row=(lane>>4)*4+reg
    const int rbase = m0 + (wm << 6) + ((lane >> 4) << 2);
    const int cbase = n0 + (wn << 6) + (lane & 15);
#pragma unroll
    for (int mi = 0; mi < 4; mi++) {
#pragma unroll
        for (int r = 0; r < 4; r++) {
            int row = rbase + (mi << 4) + r;
#pragma unroll
            for (int ni = 0; ni < 4; ni++) {
                int col = cbase + (ni << 4);
                float v = acc[mi][ni][r];
                if (MODE == 2) {
                    ((unsigned short*)out0)[(size_t)z * ((size_t)1024 * N) + (size_t)row * N + col] = f2bf(v);
                } else if (MODE == 5) {
                    atomicAdd((float*)out0 + (size_t)row * N + col, v);
                } else {
                    ((unsigned short*)outp)[(size_t)row * N + col] = f2bf(v);
                }
            }
        }
    }
}

// ---------------------------------------------------------------------------
// o-proj split-K=2 reduce + residual + RMSNorm2 fused:
//   hid[t] = hidden[t] + p0[t] + p1[t]   (fp32, written to hid)
//   xout[t] = rmsnorm(hid[t]) * ln2      (bf16)
// One block per row t.
// ---------------------------------------------------------------------------
__global__ __launch_bounds__(256)
void reduce2o_rms(const float* __restrict__ base, const unsigned short* __restrict__ part,
                  const float* __restrict__ lnw,
                  float* __restrict__ hid, unsigned short* __restrict__ xout)
{
    __shared__ float red[4];
    const int t = blockIdx.x, tid = threadIdx.x;
    const size_t stride = (size_t)1024 * 4096;
    const float4* xr = (const float4*)(base + (size_t)t * 4096);
    const uint2v* p0 = (const uint2v*)(part + (size_t)t * 4096);
    const uint2v* p1 = (const uint2v*)(part + stride + (size_t)t * 4096);
    float4* hw = (float4*)(hid + (size_t)t * 4096);
    float4 v[4];
    float ss = 0.f;
#pragma unroll
    for (int i = 0; i < 4; i++) {
        float4 a = xr[(i << 8) + tid];
        uint2v b0 = p0[(i << 8) + tid];
        uint2v b1 = p1[(i << 8) + tid];
        a.x += bf2f((unsigned short)(b0[0] & 0xFFFF)) + bf2f((unsigned short)(b1[0] & 0xFFFF));
        a.y += bf2f((unsigned short)(b0[0] >> 16))    + bf2f((unsigned short)(b1[0] >> 16));
        a.z += bf2f((unsigned short)(b0[1] & 0xFFFF)) + bf2f((unsigned short)(b1[1] & 0xFFFF));
        a.w += bf2f((unsigned short)(b0[1] >> 16))    + bf2f((unsigned short)(b1[1] >> 16));
        v[i] = a;
        ss += a.x*a.x + a.y*a.y + a.z*a.z + a.w*a.w;
        hw[(i << 8) + tid] = a;
    }
#pragma unroll
    for (int m = 1; m < 64; m <<= 1) ss += __shfl_xor(ss, m);
    if ((tid & 63) == 0) red[tid >> 6] = ss;
    __syncthreads();
    float tot = red[0] + red[1] + red[2] + red[3];
    float rs = rsqrtf(tot * (1.f / 4096.f) + 1e-6f);
    const float4* wr = (const float4*)lnw;
#pragma unroll
    for (int i = 0; i < 4; i++) {
        float4 wv = wr[(i << 8) + tid];
        unsigned int q0 = (unsigned int)f2bf(v[i].x*rs*wv.x) | ((unsigned int)f2bf(v[i].y*rs*wv.y) << 16);
        unsigned int q1 = (unsigned int)f2bf(v[i].z*rs*wv.z) | ((unsigned int)f2bf(v[i].w*rs*wv.w) << 16);
        uint2v pk = {q0, q1};
        *(uint2v*)(&xout[(size_t)t*4096 + (size_t)(((i << 8) + tid) << 2)]) = pk;
    }
}

// ---------------------------------------------------------------------------
// RoPE + layout glue
// ---------------------------------------------------------------------------
__global__ __launch_bounds__(256)
void rope_kernel(const int* __restrict__ positions, const unsigned short* __restrict__ qkv,
                 unsigned short* __restrict__ Qr, unsigned short* __restrict__ Kr,
                 unsigned short* __restrict__ Vtp)
{
    const int t = blockIdx.x, tid = threadIdx.x;
    const float p = (float)positions[t];
    const unsigned short* row = qkv + (size_t)t * 12288;
#pragma unroll 4
    for (int it = 0; it < 16; it++) {
        int task = (it << 8) + tid;
        int i   = task & 63;
        int hh  = (task >> 6) & 31;
        int isK = task >> 11;
        float fr = p * __expf(-(float)i * 0.14391156831f);
        float s, c;
        __sincosf(fr, &s, &c);
        const unsigned short* src = row + (isK << 12) + (hh << 7);
        float x1 = bf2f(src[i]);
        float x2 = bf2f(src[64 + i]);
        float o1 = x1 * c - x2 * s;
        float o2 = x2 * c + x1 * s;
        if (!isK) { o1 *= 0.08838834764831845f; o2 *= 0.08838834764831845f; }
        unsigned short* dst = (isK ? Kr : Qr) + ((size_t)hh * 1024 + t) * 128;
        dst[i]      = f2bf(o1);
        dst[64 + i] = f2bf(o2);
    }
#pragma unroll 4
    for (int it = 0; it < 16; it++) {
        int task = (it << 8) + tid;
        int d = task & 127, hh = task >> 7;
        Vtp[((size_t)hh * 128 + d) * 1024 + t] = row[8192 + task];
    }
}

// ---------------------------------------------------------------------------
// Flash attention (causal), flattened grid + deq(up) tail.
// Blocks [0,512): attn (qt = x&15, h = x>>4). Blocks >= 512: dequant.
// ---------------------------------------------------------------------------
__global__ __launch_bounds__(256, 2)
void attn_kernel(const unsigned short* __restrict__ Qr, const unsigned short* __restrict__ Kr,
                 const unsigned short* __restrict__ Vtp, unsigned short* __restrict__ attn_out,
                 int attnBlocks,
                 const int* __restrict__ dqw, const int* __restrict__ dqz,
                 const float* __restrict__ dsc, unsigned short* __restrict__ dwout,
                 int dNW, int dK)
{
    if (blockIdx.x >= (unsigned)attnBlocks) {
        int db = blockIdx.x - attnBlocks;
        int xb = dNW >> 5;
        dequant_block(db % xb, db / xb, threadIdx.x, dqw, dqz, dsc, dwout, dNW, dK);
        return;
    }
    __shared__ unsigned short Ks[64 * 128];
    __shared__ unsigned short Vs[128 * 64];
    __shared__ unsigned short Ps[4][16 * 64];
    const int tid = threadIdx.x, lane = tid & 63, w = tid >> 6;
    const int qt = blockIdx.x & 15, h = blockIdx.x >> 4;

    const unsigned short* Qh = Qr + ((size_t)h * 1024 + (size_t)qt * 64) * 128;

    bf16x8 qf[4];
#pragma unroll
    for (int kk = 0; kk < 4; kk++)
        qf[kk] = *(const bf16x8*)(Qh + (size_t)((w << 4) + (lane & 15)) * 128 + (kk << 5) + ((lane >> 4) << 3));

    f32x4 o[8];
#pragma unroll
    for (int i = 0; i < 8; i++) { f32x4 zf = {0.f,0.f,0.f,0.f}; o[i] = zf; }
    float Mr[4] = {-1e30f, -1e30f, -1e30f, -1e30f};
    float Lr[4] = {0.f, 0.f, 0.f, 0.f};
    const int qrow0 = (qt << 6) + (w << 4) + ((lane >> 4) << 2);

    for (int kt = 0; kt <= qt; kt++) {
        __syncthreads();
#pragma unroll
        for (int j = 0; j < 4; j++) {
            int slot = (j << 8) + tid;
            int rw = slot >> 4, s = slot & 15;
            int ssrc = (s & 8) | ((s ^ (rw & 7)) & 7);
            const uint4v* src = (const uint4v*)(Kr + ((size_t)h * 1024 + (size_t)kt * 64 + rw) * 128 + (ssrc << 3));
            *(uint4v*)(&Ks[(rw << 7) + (s << 3)]) = *src;
        }
#pragma unroll
        for (int j = 0; j < 4; j++) {
            int slot = (j << 8) + tid;
            int rw = slot >> 3, s = slot & 7;
            const uint4v* src = (const uint4v*)(Vtp + ((size_t)h * 128 + rw) * 1024 + (kt << 6) + ((s ^ (rw & 7)) << 3));
            *(uint4v*)(&Vs[(rw << 6) + (s << 3)]) = *src;
        }
        __syncthreads();

        f32x4 sc4[4];
#pragma unroll
        for (int ni = 0; ni < 4; ni++) { f32x4 zf = {0.f,0.f,0.f,0.f}; sc4[ni] = zf; }
#pragma unroll
        for (int kk = 0; kk < 4; kk++) {
#pragma unroll
            for (int ni = 0; ni < 4; ni++) {
                int r = (ni << 4) + (lane & 15);
                int s = (kk << 2) + (lane >> 4);
                int sp = (s & 8) | ((s ^ (r & 7)) & 7);
                bf16x8 kf = *(const bf16x8*)(&Ks[(r << 7) + (sp << 3)]);
                sc4[ni] = __builtin_amdgcn_mfma_f32_16x16x32_bf16(qf[kk], kf, sc4[ni], 0, 0, 0);
            }
        }

#pragma unroll
        for (int r = 0; r < 4; r++) {
            int qg = qrow0 + r;
            float mx = -1e30f;
#pragma unroll
            for (int ni = 0; ni < 4; ni++) {
                int kg_ = (kt << 6) + (ni << 4) + (lane & 15);
                float v = sc4[ni][r];
                if (kt == qt && kg_ > qg) { v = -1e30f; sc4[ni][r] = v; }
                mx = fmaxf(mx, v);
            }
#pragma unroll
            for (int m_ = 1; m_ < 16; m_ <<= 1) mx = fmaxf(mx, __shfl_xor(mx, m_));
            float mnew  = fmaxf(Mr[r], mx);
            float alpha = __expf(Mr[r] - mnew);
            Mr[r] = mnew;
            float rs = 0.f;
#pragma unroll
            for (int ni = 0; ni < 4; ni++) {
                float pv = __expf(sc4[ni][r] - mnew);
                sc4[ni][r] = pv;
                rs += pv;
            }
#pragma unroll
            for (int m_ = 1; m_ < 16; m_ <<= 1) rs += __shfl_xor(rs, m_);
            Lr[r] = Lr[r] * alpha + rs;
#pragma unroll
            for (int nd = 0; nd < 8; nd++) o[nd][r] *= alpha;
        }

#pragma unroll
        for (int r = 0; r < 4; r++) {
            int qr = ((lane >> 4) << 2) + r;
#pragma unroll
            for (int ni = 0; ni < 4; ni++) {
                int col = (ni << 4) + (lane & 15);
                int phys = (col >> 3) ^ (qr & 7);
                Ps[w][(qr << 6) + (phys << 3) + (col & 7)] = f2bf(sc4[ni][r]);
            }
        }
#pragma unroll
        for (int kk2 = 0; kk2 < 2; kk2++) {
            int rowp = lane & 15;
            int sl = (kk2 << 2) + (lane >> 4);
            bf16x8 pa = *(const bf16x8*)(&Ps[w][(rowp << 6) + ((sl ^ (rowp & 7)) << 3)]);
#pragma unroll
            for (int nd = 0; nd < 8; nd++) {
                int rv = (nd << 4) + (lane & 15);
                bf16x8 vb = *(const bf16x8*)(&Vs[(rv << 6) + ((sl ^ (rv & 7)) << 3)]);
                o[nd] = __builtin_amdgcn_mfma_f32_16x16x32_bf16(pa, vb, o[nd], 0, 0, 0);
            }
        }
    }

#pragma unroll
    for (int r = 0; r < 4; r++) {
        float inv = 1.0f / Lr[r];
        int trow = qrow0 + r;
#pragma unroll
        for (int nd = 0; nd < 8; nd++) {
            int col = (h << 7) + (nd << 4) + (lane & 15);
            attn_out[(size_t)trow * 4096 + col] = f2bf(o[nd][r] * inv);
        }
    }
}

// ---------------------------------------------------------------------------
// silu(gate)*up in-place into up, + dequant tail (down weights)
// ---------------------------------------------------------------------------
__global__ __launch_bounds__(256)
void silu_deq_kernel(const unsigned short* __restrict__ gate, unsigned short* __restrict__ up,
                     int siluBlocks,
                     const int* __restrict__ qw, const int* __restrict__ qz,
                     const float* __restrict__ sc, unsigned short* __restrict__ wout,
                     int NW, int K)
{
    if (blockIdx.x >= (unsigned)siluBlocks) {
        int db = blockIdx.x - siluBlocks;
        int xb = NW >> 5;
        dequant_block(db % xb, db / xb, threadIdx.x, qw, qz, sc, wout, NW, K);
        return;
    }
    size_t idx = ((size_t)blockIdx.x * 256 + threadIdx.x) * 8;
    uint4v g = *(const uint4v*)(gate + idx);
    uint4v u = *(const uint4v*)(up + idx);
    unsigned int outp[4];
#pragma unroll
    for (int j = 0; j < 4; j++) {
        unsigned int gw = g[j], uw = u[j];
        float g0 = bf2f((unsigned short)(gw & 0xFFFF)), g1 = bf2f((unsigned short)(gw >> 16));
        float u0 = bf2f((unsigned short)(uw & 0xFFFF)), u1 = bf2f((unsigned short)(uw >> 16));
        float s0 = g0 / (1.f + __expf(-g0)) * u0;
        float s1 = g1 / (1.f + __expf(-g1)) * u1;
        outp[j] = (unsigned int)f2bf(s0) | ((unsigned int)f2bf(s1) << 16);
    }
    uint4v ov = {outp[0], outp[1], outp[2], outp[3]};
    *(uint4v*)(up + idx) = ov;
}

// ---------------------------------------------------------------------------
// Launcher.  Workspace choreography (MiB offsets, peak 246):
//   [0,96)   W_qkv -> (after rope) Q[0,8) K[8,16) V[16,24) -> W_gate[0,86)
//            (written during o-gemm)
//   [86,94)  attnb
//   [96,128) W_o -> gateb[96,118)
//   [128,214) W_up
//   [214,222) xln / x2
//   [222,246) qkvb -> o-partials[222,238) -> upb[222,244)
//   hid = d_out (fp32); down-proj atomicAdds into it (MODE 5, no reduce pass)
// Every tail-dequant write region is disjoint from its carrier's reads.
// ---------------------------------------------------------------------------
extern "C" void kernel_launch(void* const* d_in, const int* in_sizes, int n_in,
                              void* d_out, int out_size, void* d_ws, size_t ws_size,
                              hipStream_t stream)
{
    const int*   positions = (const int*)  d_in[0];
    const float* hidden    = (const float*)d_in[1];
    const float* ln1       = (const float*)d_in[2];
    const float* ln2       = (const float*)d_in[3];
    const int*   qkv_qw    = (const int*)  d_in[4];
    const int*   qkv_qz    = (const int*)  d_in[5];
    const float* qkv_sc    = (const float*)d_in[6];
    const int*   o_qw      = (const int*)  d_in[7];
    const int*   o_qz      = (const int*)  d_in[8];
    const float* o_sc      = (const float*)d_in[9];
    const int*   gate_qw   = (const int*)  d_in[10];
    const int*   gate_qz   = (const int*)  d_in[11];
    const float* gate_sc   = (const float*)d_in[12];
    const int*   up_qw     = (const int*)  d_in[13];
    const int*   up_qz     = (const int*)  d_in[14];
    const float* up_sc     = (const float*)d_in[15];
    const int*   down_qw   = (const int*)  d_in[16];
    const int*   down_qz   = (const int*)  d_in[17];
    const float* down_sc   = (const float*)d_in[18];

    char* ws = (char*)d_ws;
    const size_t MB = 1 << 20;
    unsigned short* W_qkv = (unsigned short*)(ws + 0);
    unsigned short* Qrp   = (unsigned short*)(ws + 0);
    unsigned short* Krp   = (unsigned short*)(ws + 8 * MB);
    unsigned short* Vtp   = (unsigned short*)(ws + 16 * MB);
    unsigned short* W_gate= (unsigned short*)(ws + 0);
    unsigned short* W_down= (unsigned short*)(ws + 0);
    unsigned short* attnb = (unsigned short*)(ws + 86 * MB);
    unsigned short* W_o   = (unsigned short*)(ws + 96 * MB);
    unsigned short* gateb = (unsigned short*)(ws + 96 * MB);
    unsigned short* W_up  = (unsigned short*)(ws + 128 * MB);
    unsigned short* xln   = (unsigned short*)(ws + 214 * MB);
    unsigned short* qkvb  = (unsigned short*)(ws + 222 * MB);
    unsigned short* part_o= (unsigned short*)(ws + 222 * MB);   // o partials [222,238)
    unsigned short* upb   = (unsigned short*)(ws + 222 * MB);
    float*          hid   = (float*)d_out;

    // --- attention block ---
    // deq(qkv) 3072 + rmsnorm1 tail 1024
    deq_rms_kernel<<<3072 + 1024, 256, 0, stream>>>(
        qkv_qw, qkv_qz, qkv_sc, W_qkv, 1536, 4096, 3072,
        hidden, ln1, xln);
    // qkv GEMM (768) + tail: deq(o) 1024
    bt_gemm<0><<<768 + 1024, 256, 0, stream>>>(
        xln, W_qkv, nullptr, (void*)qkvb, nullptr,
        12288, 4096, 96, 768, 0,
        o_qw, o_qz, o_sc, W_o, 512, 4096);
    rope_kernel<<<1024, 256, 0, stream>>>(positions, qkvb, Qrp, Krp, Vtp);
    // attn (512) + tail: deq(up) 2752
    attn_kernel<<<512 + 2752, 256, 0, stream>>>(
        Qrp, Krp, Vtp, attnb, 512,
        up_qw, up_qz, up_sc, W_up, 1376, 4096);
    // o GEMM split-K=2 (512 gemm blocks, bf16 partials -> [222,238))
    //   + tail: deq(gate) 2752 -> [0,86)
    bt_gemm<2><<<dim3(256 + 2752, 1, 2), 256, 0, stream>>>(
        attnb, W_o, nullptr, (void*)part_o, nullptr,
        4096, 4096, 32, 256, 2048,
        gate_qw, gate_qz, gate_sc, W_gate, 1376, 4096);
    // fused: hid(d_out) = hidden + p0 + p1 ; xln = rmsnorm(hid)*ln2
    reduce2o_rms<<<1024, 256, 0, stream>>>(hidden, part_o, ln2, hid, xln);
    // --- MLP block ---
    // gate+up fused (z=2, MODE 1): 1376 blocks, the 45%-util config
    bt_gemm<1><<<dim3(688, 1, 2), 256, 0, stream>>>(
        xln, W_gate, W_up, (void*)gateb, (void*)upb,
        11008, 4096, 86, 688, 0,
        nullptr, nullptr, nullptr, nullptr, 32, 64);
    // silu(gate)*up (5504) + tail: deq(down) 2752 -> [0,86)
    silu_deq_kernel<<<5504 + 2752, 256, 0, stream>>>(
        gateb, upb, 5504, down_qw, down_qz, down_sc, W_down, 512, 11008);
    // down GEMM: split-K=4 (z), fp32 atomicAdd directly into d_out (holds hid)
    bt_gemm<5><<<dim3(256, 1, 4), 256, 0, stream>>>(
        upb, W_down, nullptr, d_out, nullptr,
        4096, 11008, 32, 256, 2752,
        nullptr, nullptr, nullptr, nullptr, 32, 64);
}

// Round 18
// 669.873 us; speedup vs baseline: 1.0303x; 1.0303x over previous
//
#include <hip/hip_runtime.h>
#include <cstdint>

// ---------------------------------------------------------------------------
// Types & helpers
// ---------------------------------------------------------------------------
typedef __attribute__((ext_vector_type(8))) short  bf16x8;   // 8 bf16 = 4 VGPR
typedef __attribute__((ext_vector_type(4))) float  f32x4;
typedef __attribute__((ext_vector_type(4))) unsigned int uint4v;
typedef __attribute__((ext_vector_type(2))) unsigned int uint2v;

typedef const __attribute__((address_space(1))) void* gas_t;
typedef __attribute__((address_space(3))) void* las_t;

__device__ __forceinline__ float bf2f(unsigned short b) {
    union { unsigned int u; float f; } v; v.u = ((unsigned int)b) << 16; return v.f;
}
__device__ __forceinline__ unsigned short f2bf(float f) {
    union { float f; unsigned int u; } v; v.f = f;
    unsigned int r = v.u + 0x7FFFu + ((v.u >> 16) & 1u);   // RNE
    return (unsigned short)(r >> 16);
}
__device__ __forceinline__ float u2f(unsigned int u) {
    union { unsigned int u; float f; } v; v.u = u; return v.f;
}

// ---------------------------------------------------------------------------
// Dequant block body: packed qw[K][NW] int4 -> Wt[N][K] bf16 (transposed).
// One block = 32 word-cols x 64 k. Thread owns 8k x 8n micro-tile.
// ---------------------------------------------------------------------------
__device__ __forceinline__ void dequant_block(int bx, int by, int t,
    const int* __restrict__ qw, const int* __restrict__ qz,
    const float* __restrict__ sc, unsigned short* __restrict__ out,
    int NW, int K)
{
    const int wcb = bx << 5;
    const int kb  = by << 6;
    const int g   = by >> 1;                  // AWQ group (G=128)
    const int N   = NW << 3;
    const int wc  = wcb + (t >> 3);
    const int k0  = kb + ((t & 7) << 3);

    unsigned int w[8];
#pragma unroll
    for (int j = 0; j < 8; j++) w[j] = (unsigned int)qw[(size_t)(k0 + j) * NW + wc];
    const unsigned int zw = (unsigned int)qz[(size_t)g * NW + wc];
    float scv[8];
#pragma unroll
    for (int j2 = 0; j2 < 8; j2++) scv[j2] = sc[(size_t)g * N + (wc << 3) + j2];

#pragma unroll
    for (int j2 = 0; j2 < 8; j2++) {
        const int sh = j2 << 2;
        const float s = scv[j2];
        const float moff = -(8388608.0f + (float)((zw >> sh) & 0xFu)) * s;
        unsigned int pk[4];
#pragma unroll
        for (int i = 0; i < 4; i++) {
            float f0 = fmaf(u2f(((w[2*i]   >> sh) & 0xFu) | 0x4B000000u), s, moff);
            float f1 = fmaf(u2f(((w[2*i+1] >> sh) & 0xFu) | 0x4B000000u), s, moff);
            asm("v_cvt_pk_bf16_f32 %0, %1, %2" : "=v"(pk[i]) : "v"(f0), "v"(f1));
        }
        uint4v ov = {pk[0], pk[1], pk[2], pk[3]};
        *(uint4v*)(out + (size_t)((wc << 3) + j2) * K + k0) = ov;
    }
}

// ---------------------------------------------------------------------------
// deq(qkv) + rmsnorm1 tail (independent work, one dispatch)
// ---------------------------------------------------------------------------
__global__ __launch_bounds__(256)
void deq_rms_kernel(const int* __restrict__ qw, const int* __restrict__ qz,
                    const float* __restrict__ sc, unsigned short* __restrict__ wout,
                    int NW, int K, int deqBlocks,
                    const float* __restrict__ x, const float* __restrict__ lnw,
                    unsigned short* __restrict__ xout)
{
    __shared__ float red[4];
    const int tid = threadIdx.x;
    if (blockIdx.x < (unsigned)deqBlocks) {
        int xb = NW >> 5;
        dequant_block(blockIdx.x % xb, blockIdx.x / xb, tid, qw, qz, sc, wout, NW, K);
        return;
    }
    const int t = blockIdx.x - deqBlocks;
    const float4* xr = (const float4*)(x + (size_t)t * 4096);
    float4 v[4];
    float ss = 0.f;
#pragma unroll
    for (int j = 0; j < 4; j++) {
        v[j] = xr[(j << 8) + tid];
        ss += v[j].x*v[j].x + v[j].y*v[j].y + v[j].z*v[j].z + v[j].w*v[j].w;
    }
#pragma unroll
    for (int m = 1; m < 64; m <<= 1) ss += __shfl_xor(ss, m);
    if ((tid & 63) == 0) red[tid >> 6] = ss;
    __syncthreads();
    float tot = red[0] + red[1] + red[2] + red[3];
    float rs = rsqrtf(tot * (1.f / 4096.f) + 1e-6f);
    const float4* wr = (const float4*)lnw;
#pragma unroll
    for (int j = 0; j < 4; j++) {
        float4 wv = wr[(j << 8) + tid];
        float4 xv = v[j];
        unsigned int p0 = (unsigned int)f2bf(xv.x*rs*wv.x) | ((unsigned int)f2bf(xv.y*rs*wv.y) << 16);
        unsigned int p1 = (unsigned int)f2bf(xv.z*rs*wv.z) | ((unsigned int)f2bf(xv.w*rs*wv.w) << 16);
        uint2v pk = {p0, p1};
        *(uint2v*)(&xout[(size_t)t*4096 + (size_t)(((j << 8) + tid) << 2)]) = pk;
    }
}

// ---------------------------------------------------------------------------
// Unified bf16 B^T GEMM (m97 structure, bijective XCD mapping) + dequant tail.
// GEMM: tile 128x128, BK=64, 4 waves, 32KB LDS, 4 blk/CU (lb 256,4 — proven;
// lb(256,5) capped VGPR at 48 and spilled acc -> 2x slowdown, R13).
//   xcd = flat&7, work = NB*xcd + (flat>>3), nb = work>>3, m = work&7.
// MODE 0: bf16 out0.  MODE 1: z picks (Bt0,out0)/(Bt1,out1), bf16.
// MODE 2: split-K by z (ksplit K each), bf16 partial at out0 + z*1024*N.
// ---------------------------------------------------------------------------
template<int MODE>
__global__ __launch_bounds__(256, 4)
void bt_gemm(const unsigned short* __restrict__ A,
             const unsigned short* __restrict__ Bt0,
             const unsigned short* __restrict__ Bt1,
             void* __restrict__ out0, void* __restrict__ out1,
             int N, int K, int NB, int gemmBlocks, int ksplit,
             const int* dq1_qw, const int* dq1_qz, const float* dq1_sc,
             unsigned short* dq1_out, int dq1_NW, int dq1_K)
{
    const int flat = blockIdx.x;
    if (flat >= gemmBlocks) {
        if (blockIdx.z != 0) return;
        int db = flat - gemmBlocks;
        int xb = dq1_NW >> 5;
        dequant_block(db % xb, db / xb, threadIdx.x, dq1_qw, dq1_qz, dq1_sc, dq1_out, dq1_NW, dq1_K);
        return;
    }

    const int work = NB * (flat & 7) + (flat >> 3);
    const int n0 = (work >> 3) << 7;
    const int m0 = (work & 7) << 7;
    const int z  = blockIdx.z;

    const unsigned short* Bt = Bt0;
    void* outp = out0;
    if (MODE == 1 && z == 1) { Bt = Bt1; outp = out1; }
    const int k0base = (MODE == 2) ? z * ksplit : 0;
    const int nsteps = ((MODE == 2) ? ksplit : K) >> 6;

    __shared__ unsigned short As[128 * 64];   // 16KB
    __shared__ unsigned short Bs[128 * 64];   // 16KB

    const int tid  = threadIdx.x;
    const int lane = tid & 63;
    const int wid  = tid >> 6;
    const int wm   = wid >> 1, wn = wid & 1;

    f32x4 acc[4][4];
#pragma unroll
    for (int i = 0; i < 4; i++)
#pragma unroll
        for (int j = 0; j < 4; j++) { f32x4 zv = {0.f,0.f,0.f,0.f}; acc[i][j] = zv; }

    for (int t = 0; t < nsteps; t++) {
        const int k0 = k0base + (t << 6);
        __syncthreads();   // previous tile's reads complete
#pragma unroll
        for (int i = 0; i < 4; i++) {
            int slot = (i << 8) + tid;          // 0..1023
            int row = slot >> 3, s = slot & 7;
            __builtin_amdgcn_global_load_lds(
                (gas_t)(A + (size_t)(m0 + row) * K + k0 + ((s ^ (row & 7)) << 3)),
                (las_t)&As[slot << 3], 16, 0, 0);
        }
#pragma unroll
        for (int i = 0; i < 4; i++) {
            int slot = (i << 8) + tid;
            int row = slot >> 3, s = slot & 7;
            __builtin_amdgcn_global_load_lds(
                (gas_t)(Bt + (size_t)(n0 + row) * K + k0 + ((s ^ (row & 7)) << 3)),
                (las_t)&Bs[slot << 3], 16, 0, 0);
        }
        __syncthreads();   // drains vmcnt: tile resident
#pragma unroll
        for (int kk = 0; kk < 2; kk++) {
            const int srow = (kk << 2) + (lane >> 4);
            bf16x8 af[4], bfv[4];
#pragma unroll
            for (int mi = 0; mi < 4; mi++) {
                int r = (wm << 6) + (mi << 4) + (lane & 15);
                af[mi] = *(const bf16x8*)(&As[(r << 6) + ((srow ^ (r & 7)) << 3)]);
            }
#pragma unroll
            for (int ni = 0; ni < 4; ni++) {
                int r = (wn << 6) + (ni << 4) + (lane & 15);
                bfv[ni] = *(const bf16x8*)(&Bs[(r << 6) + ((srow ^ (r & 7)) << 3)]);
            }
#pragma unroll
            for (int mi = 0; mi < 4; mi++)
#pragma unroll
                for (int ni = 0; ni < 4; ni++)
                    acc[mi][ni] = __builtin_amdgcn_mfma_f32_16x16x32_bf16(af[mi], bfv[ni], acc[mi][ni], 0, 0, 0);
        }
    }

    // epilogue: C/D layout col=lane&15, row=(lane>>4)*4+reg
    const int rbase = m0 + (wm << 6) + ((lane >> 4) << 2);
    const int cbase = n0 + (wn << 6) + (lane & 15);
#pragma unroll
    for (int mi = 0; mi < 4; mi++) {
#pragma unroll
        for (int r = 0; r < 4; r++) {
            int row = rbase + (mi << 4) + r;
#pragma unroll
            for (int ni = 0; ni < 4; ni++) {
                int col = cbase + (ni << 4);
                float v = acc[mi][ni][r];
                if (MODE == 2) {
                    ((unsigned short*)out0)[(size_t)z * ((size_t)1024 * N) + (size_t)row * N + col] = f2bf(v);
                } else {
                    ((unsigned short*)outp)[(size_t)row * N + col] = f2bf(v);
                }
            }
        }
    }
}

// ---------------------------------------------------------------------------
// o-proj split-K=2 reduce + residual + RMSNorm2 fused:
//   hid[t] = hidden[t] + p0[t] + p1[t]   (fp32, written to hid)
//   xout[t] = rmsnorm(hid[t]) * ln2      (bf16)
// One block per row t.
// ---------------------------------------------------------------------------
__global__ __launch_bounds__(256)
void reduce2o_rms(const float* __restrict__ base, const unsigned short* __restrict__ part,
                  const float* __restrict__ lnw,
                  float* __restrict__ hid, unsigned short* __restrict__ xout)
{
    __shared__ float red[4];
    const int t = blockIdx.x, tid = threadIdx.x;
    const size_t stride = (size_t)1024 * 4096;
    const float4* xr = (const float4*)(base + (size_t)t * 4096);
    const uint2v* p0 = (const uint2v*)(part + (size_t)t * 4096);
    const uint2v* p1 = (const uint2v*)(part + stride + (size_t)t * 4096);
    float4* hw = (float4*)(hid + (size_t)t * 4096);
    float4 v[4];
    float ss = 0.f;
#pragma unroll
    for (int i = 0; i < 4; i++) {
        float4 a = xr[(i << 8) + tid];
        uint2v b0 = p0[(i << 8) + tid];
        uint2v b1 = p1[(i << 8) + tid];
        a.x += bf2f((unsigned short)(b0[0] & 0xFFFF)) + bf2f((unsigned short)(b1[0] & 0xFFFF));
        a.y += bf2f((unsigned short)(b0[0] >> 16))    + bf2f((unsigned short)(b1[0] >> 16));
        a.z += bf2f((unsigned short)(b0[1] & 0xFFFF)) + bf2f((unsigned short)(b1[1] & 0xFFFF));
        a.w += bf2f((unsigned short)(b0[1] >> 16))    + bf2f((unsigned short)(b1[1] >> 16));
        v[i] = a;
        ss += a.x*a.x + a.y*a.y + a.z*a.z + a.w*a.w;
        hw[(i << 8) + tid] = a;
    }
#pragma unroll
    for (int m = 1; m < 64; m <<= 1) ss += __shfl_xor(ss, m);
    if ((tid & 63) == 0) red[tid >> 6] = ss;
    __syncthreads();
    float tot = red[0] + red[1] + red[2] + red[3];
    float rs = rsqrtf(tot * (1.f / 4096.f) + 1e-6f);
    const float4* wr = (const float4*)lnw;
#pragma unroll
    for (int i = 0; i < 4; i++) {
        float4 wv = wr[(i << 8) + tid];
        unsigned int q0 = (unsigned int)f2bf(v[i].x*rs*wv.x) | ((unsigned int)f2bf(v[i].y*rs*wv.y) << 16);
        unsigned int q1 = (unsigned int)f2bf(v[i].z*rs*wv.z) | ((unsigned int)f2bf(v[i].w*rs*wv.w) << 16);
        uint2v pk = {q0, q1};
        *(uint2v*)(&xout[(size_t)t*4096 + (size_t)(((i << 8) + tid) << 2)]) = pk;
    }
}

// ---------------------------------------------------------------------------
// Split-K=4 reduce: out = base + sum of 4 bf16 partials (each 1024x4096)
// ---------------------------------------------------------------------------
__global__ __launch_bounds__(256)
void reduce4_kernel(const float* __restrict__ base, const unsigned short* __restrict__ part,
                    float* __restrict__ out)
{
    const size_t i = (size_t)blockIdx.x * 256 + threadIdx.x;   // 8 elems/thread
    const size_t stride = (size_t)1024 * 4096;
    float s[8];
    float4 a0 = ((const float4*)base)[2*i], a1 = ((const float4*)base)[2*i+1];
    s[0]=a0.x; s[1]=a0.y; s[2]=a0.z; s[3]=a0.w; s[4]=a1.x; s[5]=a1.y; s[6]=a1.z; s[7]=a1.w;
#pragma unroll
    for (int p = 0; p < 4; p++) {
        uint4v v = *(const uint4v*)(part + p * stride + i * 8);
#pragma unroll
        for (int j = 0; j < 4; j++) {
            s[2*j]   += bf2f((unsigned short)(v[j] & 0xFFFF));
            s[2*j+1] += bf2f((unsigned short)(v[j] >> 16));
        }
    }
    float4 o0 = {s[0],s[1],s[2],s[3]}, o1 = {s[4],s[5],s[6],s[7]};
    ((float4*)out)[2*i] = o0; ((float4*)out)[2*i+1] = o1;
}

// ---------------------------------------------------------------------------
// RoPE + layout glue
// ---------------------------------------------------------------------------
__global__ __launch_bounds__(256)
void rope_kernel(const int* __restrict__ positions, const unsigned short* __restrict__ qkv,
                 unsigned short* __restrict__ Qr, unsigned short* __restrict__ Kr,
                 unsigned short* __restrict__ Vtp)
{
    const int t = blockIdx.x, tid = threadIdx.x;
    const float p = (float)positions[t];
    const unsigned short* row = qkv + (size_t)t * 12288;
#pragma unroll 4
    for (int it = 0; it < 16; it++) {
        int task = (it << 8) + tid;
        int i   = task & 63;
        int hh  = (task >> 6) & 31;
        int isK = task >> 11;
        float fr = p * __expf(-(float)i * 0.14391156831f);
        float s, c;
        __sincosf(fr, &s, &c);
        const unsigned short* src = row + (isK << 12) + (hh << 7);
        float x1 = bf2f(src[i]);
        float x2 = bf2f(src[64 + i]);
        float o1 = x1 * c - x2 * s;
        float o2 = x2 * c + x1 * s;
        if (!isK) { o1 *= 0.08838834764831845f; o2 *= 0.08838834764831845f; }
        unsigned short* dst = (isK ? Kr : Qr) + ((size_t)hh * 1024 + t) * 128;
        dst[i]      = f2bf(o1);
        dst[64 + i] = f2bf(o2);
    }
#pragma unroll 4
    for (int it = 0; it < 16; it++) {
        int task = (it << 8) + tid;
        int d = task & 127, hh = task >> 7;
        Vtp[((size_t)hh * 128 + d) * 1024 + t] = row[8192 + task];
    }
}

// ---------------------------------------------------------------------------
// Flash attention (causal), flattened grid + deq(up) tail.
// Blocks [0,512): attn (qt = x&15, h = x>>4). Blocks >= 512: dequant.
// ---------------------------------------------------------------------------
__global__ __launch_bounds__(256, 2)
void attn_kernel(const unsigned short* __restrict__ Qr, const unsigned short* __restrict__ Kr,
                 const unsigned short* __restrict__ Vtp, unsigned short* __restrict__ attn_out,
                 int attnBlocks,
                 const int* __restrict__ dqw, const int* __restrict__ dqz,
                 const float* __restrict__ dsc, unsigned short* __restrict__ dwout,
                 int dNW, int dK)
{
    if (blockIdx.x >= (unsigned)attnBlocks) {
        int db = blockIdx.x - attnBlocks;
        int xb = dNW >> 5;
        dequant_block(db % xb, db / xb, threadIdx.x, dqw, dqz, dsc, dwout, dNW, dK);
        return;
    }
    __shared__ unsigned short Ks[64 * 128];
    __shared__ unsigned short Vs[128 * 64];
    __shared__ unsigned short Ps[4][16 * 64];
    const int tid = threadIdx.x, lane = tid & 63, w = tid >> 6;
    const int qt = blockIdx.x & 15, h = blockIdx.x >> 4;

    const unsigned short* Qh = Qr + ((size_t)h * 1024 + (size_t)qt * 64) * 128;

    bf16x8 qf[4];
#pragma unroll
    for (int kk = 0; kk < 4; kk++)
        qf[kk] = *(const bf16x8*)(Qh + (size_t)((w << 4) + (lane & 15)) * 128 + (kk << 5) + ((lane >> 4) << 3));

    f32x4 o[8];
#pragma unroll
    for (int i = 0; i < 8; i++) { f32x4 zf = {0.f,0.f,0.f,0.f}; o[i] = zf; }
    float Mr[4] = {-1e30f, -1e30f, -1e30f, -1e30f};
    float Lr[4] = {0.f, 0.f, 0.f, 0.f};
    const int qrow0 = (qt << 6) + (w << 4) + ((lane >> 4) << 2);

    for (int kt = 0; kt <= qt; kt++) {
        __syncthreads();
#pragma unroll
        for (int j = 0; j < 4; j++) {
            int slot = (j << 8) + tid;
            int rw = slot >> 4, s = slot & 15;
            int ssrc = (s & 8) | ((s ^ (rw & 7)) & 7);
            const uint4v* src = (const uint4v*)(Kr + ((size_t)h * 1024 + (size_t)kt * 64 + rw) * 128 + (ssrc << 3));
            *(uint4v*)(&Ks[(rw << 7) + (s << 3)]) = *src;
        }
#pragma unroll
        for (int j = 0; j < 4; j++) {
            int slot = (j << 8) + tid;
            int rw = slot >> 3, s = slot & 7;
            const uint4v* src = (const uint4v*)(Vtp + ((size_t)h * 128 + rw) * 1024 + (kt << 6) + ((s ^ (rw & 7)) << 3));
            *(uint4v*)(&Vs[(rw << 6) + (s << 3)]) = *src;
        }
        __syncthreads();

        f32x4 sc4[4];
#pragma unroll
        for (int ni = 0; ni < 4; ni++) { f32x4 zf = {0.f,0.f,0.f,0.f}; sc4[ni] = zf; }
#pragma unroll
        for (int kk = 0; kk < 4; kk++) {
#pragma unroll
            for (int ni = 0; ni < 4; ni++) {
                int r = (ni << 4) + (lane & 15);
                int s = (kk << 2) + (lane >> 4);
                int sp = (s & 8) | ((s ^ (r & 7)) & 7);
                bf16x8 kf = *(const bf16x8*)(&Ks[(r << 7) + (sp << 3)]);
                sc4[ni] = __builtin_amdgcn_mfma_f32_16x16x32_bf16(qf[kk], kf, sc4[ni], 0, 0, 0);
            }
        }

#pragma unroll
        for (int r = 0; r < 4; r++) {
            int qg = qrow0 + r;
            float mx = -1e30f;
#pragma unroll
            for (int ni = 0; ni < 4; ni++) {
                int kg_ = (kt << 6) + (ni << 4) + (lane & 15);
                float v = sc4[ni][r];
                if (kt == qt && kg_ > qg) { v = -1e30f; sc4[ni][r] = v; }
                mx = fmaxf(mx, v);
            }
#pragma unroll
            for (int m_ = 1; m_ < 16; m_ <<= 1) mx = fmaxf(mx, __shfl_xor(mx, m_));
            float mnew  = fmaxf(Mr[r], mx);
            float alpha = __expf(Mr[r] - mnew);
            Mr[r] = mnew;
            float rs = 0.f;
#pragma unroll
            for (int ni = 0; ni < 4; ni++) {
                float pv = __expf(sc4[ni][r] - mnew);
                sc4[ni][r] = pv;
                rs += pv;
            }
#pragma unroll
            for (int m_ = 1; m_ < 16; m_ <<= 1) rs += __shfl_xor(rs, m_);
            Lr[r] = Lr[r] * alpha + rs;
#pragma unroll
            for (int nd = 0; nd < 8; nd++) o[nd][r] *= alpha;
        }

#pragma unroll
        for (int r = 0; r < 4; r++) {
            int qr = ((lane >> 4) << 2) + r;
#pragma unroll
            for (int ni = 0; ni < 4; ni++) {
                int col = (ni << 4) + (lane & 15);
                int phys = (col >> 3) ^ (qr & 7);
                Ps[w][(qr << 6) + (phys << 3) + (col & 7)] = f2bf(sc4[ni][r]);
            }
        }
#pragma unroll
        for (int kk2 = 0; kk2 < 2; kk2++) {
            int rowp = lane & 15;
            int sl = (kk2 << 2) + (lane >> 4);
            bf16x8 pa = *(const bf16x8*)(&Ps[w][(rowp << 6) + ((sl ^ (rowp & 7)) << 3)]);
#pragma unroll
            for (int nd = 0; nd < 8; nd++) {
                int rv = (nd << 4) + (lane & 15);
                bf16x8 vb = *(const bf16x8*)(&Vs[(rv << 6) + ((sl ^ (rv & 7)) << 3)]);
                o[nd] = __builtin_amdgcn_mfma_f32_16x16x32_bf16(pa, vb, o[nd], 0, 0, 0);
            }
        }
    }

#pragma unroll
    for (int r = 0; r < 4; r++) {
        float inv = 1.0f / Lr[r];
        int trow = qrow0 + r;
#pragma unroll
        for (int nd = 0; nd < 8; nd++) {
            int col = (h << 7) + (nd << 4) + (lane & 15);
            attn_out[(size_t)trow * 4096 + col] = f2bf(o[nd][r] * inv);
        }
    }
}

// ---------------------------------------------------------------------------
// silu(gate)*up in-place into up, + dequant tail (down weights)
// ---------------------------------------------------------------------------
__global__ __launch_bounds__(256)
void silu_deq_kernel(const unsigned short* __restrict__ gate, unsigned short* __restrict__ up,
                     int siluBlocks,
                     const int* __restrict__ qw, const int* __restrict__ qz,
                     const float* __restrict__ sc, unsigned short* __restrict__ wout,
                     int NW, int K)
{
    if (blockIdx.x >= (unsigned)siluBlocks) {
        int db = blockIdx.x - siluBlocks;
        int xb = NW >> 5;
        dequant_block(db % xb, db / xb, threadIdx.x, qw, qz, sc, wout, NW, K);
        return;
    }
    size_t idx = ((size_t)blockIdx.x * 256 + threadIdx.x) * 8;
    uint4v g = *(const uint4v*)(gate + idx);
    uint4v u = *(const uint4v*)(up + idx);
    unsigned int outp[4];
#pragma unroll
    for (int j = 0; j < 4; j++) {
        unsigned int gw = g[j], uw = u[j];
        float g0 = bf2f((unsigned short)(gw & 0xFFFF)), g1 = bf2f((unsigned short)(gw >> 16));
        float u0 = bf2f((unsigned short)(uw & 0xFFFF)), u1 = bf2f((unsigned short)(uw >> 16));
        float s0 = g0 / (1.f + __expf(-g0)) * u0;
        float s1 = g1 / (1.f + __expf(-g1)) * u1;
        outp[j] = (unsigned int)f2bf(s0) | ((unsigned int)f2bf(s1) << 16);
    }
    uint4v ov = {outp[0], outp[1], outp[2], outp[3]};
    *(uint4v*)(up + idx) = ov;
}

// ---------------------------------------------------------------------------
// Launcher.  Workspace choreography (MiB offsets, peak 246):
//   [0,96)   W_qkv -> (after rope) Q[0,8) K[8,16) V[16,24) -> W_gate[0,86)
//            (written during o-gemm)
//   [86,94)  attnb
//   [96,128) W_o -> gateb[96,118) -> down-partials[96,128)
//   [128,214) W_up
//   [214,222) xln / x2
//   [222,246) qkvb -> o-partials[222,238) -> upb[222,244)
//   hid = d_out (fp32)
// Every tail-dequant write region is disjoint from its carrier's reads.
// ---------------------------------------------------------------------------
extern "C" void kernel_launch(void* const* d_in, const int* in_sizes, int n_in,
                              void* d_out, int out_size, void* d_ws, size_t ws_size,
                              hipStream_t stream)
{
    const int*   positions = (const int*)  d_in[0];
    const float* hidden    = (const float*)d_in[1];
    const float* ln1       = (const float*)d_in[2];
    const float* ln2       = (const float*)d_in[3];
    const int*   qkv_qw    = (const int*)  d_in[4];
    const int*   qkv_qz    = (const int*)  d_in[5];
    const float* qkv_sc    = (const float*)d_in[6];
    const int*   o_qw      = (const int*)  d_in[7];
    const int*   o_qz      = (const int*)  d_in[8];
    const float* o_sc      = (const float*)d_in[9];
    const int*   gate_qw   = (const int*)  d_in[10];
    const int*   gate_qz   = (const int*)  d_in[11];
    const float* gate_sc   = (const float*)d_in[12];
    const int*   up_qw     = (const int*)  d_in[13];
    const int*   up_qz     = (const int*)  d_in[14];
    const float* up_sc     = (const float*)d_in[15];
    const int*   down_qw   = (const int*)  d_in[16];
    const int*   down_qz   = (const int*)  d_in[17];
    const float* down_sc   = (const float*)d_in[18];

    char* ws = (char*)d_ws;
    const size_t MB = 1 << 20;
    unsigned short* W_qkv = (unsigned short*)(ws + 0);
    unsigned short* Qrp   = (unsigned short*)(ws + 0);
    unsigned short* Krp   = (unsigned short*)(ws + 8 * MB);
    unsigned short* Vtp   = (unsigned short*)(ws + 16 * MB);
    unsigned short* W_gate= (unsigned short*)(ws + 0);
    unsigned short* W_down= (unsigned short*)(ws + 0);
    unsigned short* attnb = (unsigned short*)(ws + 86 * MB);
    unsigned short* W_o   = (unsigned short*)(ws + 96 * MB);
    unsigned short* gateb = (unsigned short*)(ws + 96 * MB);
    unsigned short* part  = (unsigned short*)(ws + 96 * MB);    // down partials [96,128)
    unsigned short* W_up  = (unsigned short*)(ws + 128 * MB);
    unsigned short* xln   = (unsigned short*)(ws + 214 * MB);
    unsigned short* qkvb  = (unsigned short*)(ws + 222 * MB);
    unsigned short* part_o= (unsigned short*)(ws + 222 * MB);   // o partials [222,238)
    unsigned short* upb   = (unsigned short*)(ws + 222 * MB);
    float*          hid   = (float*)d_out;

    // --- attention block ---
    // deq(qkv) 3072 + rmsnorm1 tail 1024
    deq_rms_kernel<<<3072 + 1024, 256, 0, stream>>>(
        qkv_qw, qkv_qz, qkv_sc, W_qkv, 1536, 4096, 3072,
        hidden, ln1, xln);
    // qkv GEMM (768) + tail: deq(o) 1024
    bt_gemm<0><<<768 + 1024, 256, 0, stream>>>(
        xln, W_qkv, nullptr, (void*)qkvb, nullptr,
        12288, 4096, 96, 768, 0,
        o_qw, o_qz, o_sc, W_o, 512, 4096);
    rope_kernel<<<1024, 256, 0, stream>>>(positions, qkvb, Qrp, Krp, Vtp);
    // attn (512) + tail: deq(up) 2752
    attn_kernel<<<512 + 2752, 256, 0, stream>>>(
        Qrp, Krp, Vtp, attnb, 512,
        up_qw, up_qz, up_sc, W_up, 1376, 4096);
    // o GEMM split-K=2 (512 gemm blocks, bf16 partials -> [222,238))
    //   + tail: deq(gate) 2752 -> [0,86)
    bt_gemm<2><<<dim3(256 + 2752, 1, 2), 256, 0, stream>>>(
        attnb, W_o, nullptr, (void*)part_o, nullptr,
        4096, 4096, 32, 256, 2048,
        gate_qw, gate_qz, gate_sc, W_gate, 1376, 4096);
    // fused: hid = hidden + p0 + p1 ; xln = rmsnorm(hid)*ln2
    reduce2o_rms<<<1024, 256, 0, stream>>>(hidden, part_o, ln2, hid, xln);
    // --- MLP block ---
    // gate+up fused (z=2, MODE 1): 1376 blocks, the 45%-util config
    bt_gemm<1><<<dim3(688, 1, 2), 256, 0, stream>>>(
        xln, W_gate, W_up, (void*)gateb, (void*)upb,
        11008, 4096, 86, 688, 0,
        nullptr, nullptr, nullptr, nullptr, 32, 64);
    // silu(gate)*up (5504) + tail: deq(down) 2752 -> [0,86)
    silu_deq_kernel<<<5504 + 2752, 256, 0, stream>>>(
        gateb, upb, 5504, down_qw, down_qz, down_sc, W_down, 512, 11008);
    // down GEMM: split-K=4 (z), bf16 partials at [96,128)
    bt_gemm<2><<<dim3(256, 1, 4), 256, 0, stream>>>(
        upb, W_down, nullptr, (void*)part, nullptr,
        4096, 11008, 32, 256, 2752,
        nullptr, nullptr, nullptr, nullptr, 32, 64);
    reduce4_kernel<<<2048, 256, 0, stream>>>(hid, part, (float*)d_out);
}